// Round 5
// baseline (422.739 us; speedup 1.0000x reference)
//
#include <hip/hip_runtime.h>
#include <hip/hip_fp16.h>

#define D 64
#define EPS 1e-5f

// CSR bucketing params: buckets of 512 consecutive dst nodes
#define BK_SHIFT 9
#define BK_W 512
#define NBMAX 256        // supports n up to 131072
#define BK_CAP 8192      // avg 6144 edges/bucket
#define CHUNK 4096       // edges per bucket_k block

// ---------------- Phase A: bucketize edges; pack (src<<9 | dst_local) ----------------

__global__ __launch_bounds__(256) void bucket_k(const int* __restrict__ src,
                                                const int* __restrict__ dst,
                                                int* __restrict__ bcnt,
                                                int* __restrict__ pairs,
                                                int e, int nbk) {
  __shared__ int hcnt[NBMAX];
  __shared__ int hbase[NBMAX];
  const int t = threadIdx.x;
  const int e0 = blockIdx.x * CHUNK;
  const int e1 = min(e0 + CHUNK, e);
  for (int i = t; i < nbk; i += 256) hcnt[i] = 0;
  __syncthreads();
  for (int i = e0 + t; i < e1; i += 256)
    atomicAdd(&hcnt[dst[i] >> BK_SHIFT], 1);
  __syncthreads();
  for (int i = t; i < nbk; i += 256) {
    int c = hcnt[i];
    hbase[i] = c ? atomicAdd(&bcnt[i], c) : 0;
    hcnt[i] = 0;   // reuse as cursor
  }
  __syncthreads();
  for (int i = e0 + t; i < e1; i += 256) {
    int s = src[i], d = dst[i];
    int b = d >> BK_SHIFT;
    int r = hbase[b] + atomicAdd(&hcnt[b], 1);
    if (r < BK_CAP) pairs[(size_t)b * BK_CAP + r] = (s << BK_SHIFT) | (d & (BK_W - 1));
  }
}

// ---------------- Phase B1: per-bucket histogram -> cnt ----------------

__global__ __launch_bounds__(256) void bhist_k(const int* __restrict__ bcnt,
                                               const int* __restrict__ pairs,
                                               int* __restrict__ cnt, int n) {
  __shared__ int h[BK_W];
  const int b = blockIdx.x, t = threadIdx.x;
  const int base = b << BK_SHIFT;
  const int m = min(bcnt[b], BK_CAP);
  for (int i = t; i < BK_W; i += 256) h[i] = 0;
  __syncthreads();
  const int* p = pairs + (size_t)b * BK_CAP;
  for (int i = t; i < m; i += 256) atomicAdd(&h[p[i] & (BK_W - 1)], 1);
  __syncthreads();
  for (int i = t; i < BK_W && base + i < n; i += 256) cnt[base + i] = h[i];
}

// ---------------- scans ----------------

__global__ void scan_a_k(const int* __restrict__ cnt, int* __restrict__ rp,
                         int* __restrict__ bsum, int n) {
  __shared__ int sm[256];
  int t = threadIdx.x, i = blockIdx.x * 256 + t;
  int v = (i < n) ? cnt[i] : 0;
  sm[t] = v; __syncthreads();
  for (int off = 1; off < 256; off <<= 1) {
    int x = (t >= off) ? sm[t - off] : 0; __syncthreads();
    sm[t] += x; __syncthreads();
  }
  if (i < n) rp[i] = sm[t] - v;
  if (t == 255) bsum[blockIdx.x] = sm[t];
}

__global__ void scan_b_k(const int* __restrict__ bsum, int* __restrict__ boff, int nb) {
  __shared__ int sm[512];
  int t = threadIdx.x;
  int v = (t < nb) ? bsum[t] : 0;
  sm[t] = v; __syncthreads();
  for (int off = 1; off < 512; off <<= 1) {
    int x = (t >= off) ? sm[t - off] : 0; __syncthreads();
    sm[t] += x; __syncthreads();
  }
  boff[t] = sm[t] - v;
}

__global__ void scan_c_k(const int* __restrict__ cnt, int* __restrict__ rp,
                         const int* __restrict__ boff,
                         float* __restrict__ dis, int n, int etot) {
  int i = blockIdx.x * blockDim.x + threadIdx.x;
  if (i < n) {
    rp[i] = rp[i] + boff[i >> 8];
    dis[i] = rsqrtf((float)cnt[i] + 1.0f);
  }
  if (i == 0) rp[n] = etot;
}

// ---------------- Phase B2: place into CSR ----------------

__global__ __launch_bounds__(256) void place_k(const int* __restrict__ bcnt,
                                               const int* __restrict__ pairs,
                                               const int* __restrict__ rp,
                                               int* __restrict__ col, int n) {
  __shared__ int cur[BK_W];
  __shared__ int stage[BK_CAP];
  const int b = blockIdx.x, t = threadIdx.x;
  const int base = b << BK_SHIFT;
  const int out0 = rp[base];
  const int m = min(bcnt[b], BK_CAP);
  for (int i = t; i < BK_W; i += 256) {
    int node = base + i;
    cur[i] = (node < n) ? rp[node] - out0 : 0;
  }
  __syncthreads();
  const int* p = pairs + (size_t)b * BK_CAP;
  for (int i = t; i < m; i += 256) {
    int pk = p[i];
    int r = atomicAdd(&cur[pk & (BK_W - 1)], 1);
    stage[r] = pk >> BK_SHIFT;
  }
  __syncthreads();
  for (int i = t; i < m; i += 256) col[out0 + i] = stage[i];
}

// ---------------- BN/bias folding ----------------

__global__ void bnprep_k(const float* __restrict__ b1, const float* __restrict__ b2,
                         const float* __restrict__ b3,
                         const float* __restrict__ g1, const float* __restrict__ be1,
                         const float* __restrict__ rm1, const float* __restrict__ rv1,
                         const float* __restrict__ g2, const float* __restrict__ be2,
                         const float* __restrict__ rm2, const float* __restrict__ rv2,
                         float* __restrict__ scsh) {
  int t = threadIdx.x;
  int j = t & 63, l = t >> 6;
  float sc, sh;
  if (l == 0)      { sc = g1[j] * rsqrtf(rv1[j] + EPS); sh = (b1[j] - rm1[j]) * sc + be1[j]; }
  else if (l == 1) { sc = g2[j] * rsqrtf(rv2[j] + EPS); sh = (b2[j] - rm2[j]) * sc + be2[j]; }
  else             { sc = 1.0f;                          sh = b3[j]; }
  scsh[l * 128 + j] = sc;
  scsh[l * 128 + 64 + j] = sh;
}

// ---------------- GEMM: out[r] = dis[r] * (in[r] @ W), fp16 out, fp32/fp16 in --------

#define GT_R 128
#define XT_LD 132

__device__ inline float ld1(const float* p)  { return *p; }
__device__ inline float ld1(const __half* p) { return __half2float(*p); }

template <typename InT>
__global__ __launch_bounds__(256) void gemm_k(const InT* __restrict__ in,
                                              const float* __restrict__ W,
                                              const float* __restrict__ dis,
                                              __half* __restrict__ out, int nrows) {
  __shared__ float ws[64 * 64];
  __shared__ float xt[64 * XT_LD];
  __shared__ float dtile[GT_R];

  const int t    = threadIdx.x;
  const int lane = t & 63;
  const int w    = t >> 6;
  const int row0 = blockIdx.x * GT_R;

  for (int i = t; i < 1024; i += 256)
    ((float4*)ws)[i] = ((const float4*)W)[i];

  if (t < GT_R) {
    int r = row0 + t;
    dtile[t] = (r < nrows) ? dis[r] : 0.f;
  }

#pragma unroll
  for (int j = 0; j < 8; ++j) {
    int Q = w + 4 * j;
    int r = row0 + 4 * Q;
    float4 v;
    v.x = (r + 0 < nrows) ? ld1(&in[(size_t)(r + 0) * D + lane]) : 0.f;
    v.y = (r + 1 < nrows) ? ld1(&in[(size_t)(r + 1) * D + lane]) : 0.f;
    v.z = (r + 2 < nrows) ? ld1(&in[(size_t)(r + 2) * D + lane]) : 0.f;
    v.w = (r + 3 < nrows) ? ld1(&in[(size_t)(r + 3) * D + lane]) : 0.f;
    *(float4*)&xt[lane * XT_LD + 4 * Q] = v;
  }
  __syncthreads();

  const int cq = (t & 15) * 4;
  const int rg = (t >> 4) * 8;
  float acc[8][4] = {};

#pragma unroll 4
  for (int k = 0; k < 64; ++k) {
    float4 b   = *(const float4*)&ws[k * 64 + cq];
    float4 alo = *(const float4*)&xt[k * XT_LD + rg];
    float4 ahi = *(const float4*)&xt[k * XT_LD + rg + 4];
    const float ar[8] = {alo.x, alo.y, alo.z, alo.w, ahi.x, ahi.y, ahi.z, ahi.w};
#pragma unroll
    for (int i = 0; i < 8; ++i) {
      acc[i][0] = fmaf(ar[i], b.x, acc[i][0]);
      acc[i][1] = fmaf(ar[i], b.y, acc[i][1]);
      acc[i][2] = fmaf(ar[i], b.z, acc[i][2]);
      acc[i][3] = fmaf(ar[i], b.w, acc[i][3]);
    }
  }

#pragma unroll
  for (int i = 0; i < 8; ++i) {
    int r = row0 + rg + i;
    if (r < nrows) {
      float dsc = dtile[rg + i];
      union { __half2 h[2]; float2 f; } u;
      u.h[0] = __floats2half2_rn(dsc * acc[i][0], dsc * acc[i][1]);
      u.h[1] = __floats2half2_rn(dsc * acc[i][2], dsc * acc[i][3]);
      *(float2*)&out[(size_t)r * D + cq] = u.f;
    }
  }
}

// ---------------- Aggregation: 2 nodes/wave, half2 gathers, 4 accumulators ----------
// h2s pre-scaled by dis[src]. Half-wave h (lanes 32h..32h+31) owns node 2*wid+h;
// lane sl covers features 2sl, 2sl+1. out = maybe_relu((di*(self+sum))*sc + sh).

template <bool RELU, typename OutT>
__global__ __launch_bounds__(256) void agg_k(const __half* __restrict__ h2s,
                                             const int* __restrict__ rp,
                                             const int* __restrict__ col,
                                             const float* __restrict__ dis,
                                             const float* __restrict__ scsh,
                                             OutT* __restrict__ out, int n) {
  const int lane = threadIdx.x & 63;
  const int wid  = (blockIdx.x * blockDim.x + threadIdx.x) >> 6;
  const int half = lane >> 5;
  const int sl   = lane & 31;
  const int nodeA = wid * 2;
  if (nodeA >= n) return;
  const int mynode = min(nodeA + half, n - 1);

  const __half2* __restrict__ h2v = (const __half2*)h2s;

  float2 a0 = __half22float2(h2v[(size_t)mynode * 32 + sl]);   // self term
  float2 a1 = make_float2(0.f, 0.f);
  float2 a2 = make_float2(0.f, 0.f);
  float2 a3 = make_float2(0.f, 0.f);

  const int p0  = rp[mynode];
  const int deg = rp[mynode + 1] - p0;
  const int maxdeg = max(__builtin_amdgcn_readlane(deg, 0),
                         __builtin_amdgcn_readlane(deg, 32));

  for (int c = 0; c < maxdeg; c += 32) {
    const int rem = deg - c;                    // per half-wave
    int idxv = 0;
    if (sl < rem) idxv = col[p0 + c + sl];
    const int mchunk = min(maxdeg - c, 32);     // wave-uniform
    int e = 0;
    for (; e + 3 < mchunk; e += 4) {
      int s0 = __shfl(idxv, e, 32);
      int s1 = __shfl(idxv, e + 1, 32);
      int s2 = __shfl(idxv, e + 2, 32);
      int s3 = __shfl(idxv, e + 3, 32);
      float2 v0 = make_float2(0.f, 0.f), v1 = v0, v2 = v0, v3 = v0;
      if (e + 0 < rem) v0 = __half22float2(h2v[(size_t)s0 * 32 + sl]);
      if (e + 1 < rem) v1 = __half22float2(h2v[(size_t)s1 * 32 + sl]);
      if (e + 2 < rem) v2 = __half22float2(h2v[(size_t)s2 * 32 + sl]);
      if (e + 3 < rem) v3 = __half22float2(h2v[(size_t)s3 * 32 + sl]);
      a0.x += v0.x; a0.y += v0.y;
      a1.x += v1.x; a1.y += v1.y;
      a2.x += v2.x; a2.y += v2.y;
      a3.x += v3.x; a3.y += v3.y;
    }
    for (; e < mchunk; ++e) {
      int s = __shfl(idxv, e, 32);
      if (e < rem) {
        float2 v = __half22float2(h2v[(size_t)s * 32 + sl]);
        a0.x += v.x; a0.y += v.y;
      }
    }
  }

  float sx = (a0.x + a1.x) + (a2.x + a3.x);
  float sy = (a0.y + a1.y) + (a2.y + a3.y);
  const float di = dis[mynode];
  const float2 sc = ((const float2*)scsh)[sl];
  const float2 sh = ((const float2*)(scsh + 64))[sl];
  float rx = fmaf(di * sx, sc.x, sh.x);
  float ry = fmaf(di * sy, sc.y, sh.y);
  if (RELU) { rx = fmaxf(rx, 0.f); ry = fmaxf(ry, 0.f); }

  if (nodeA + half < n) {
    if constexpr (sizeof(OutT) == 2) {
      *(__half2*)&out[(size_t)mynode * D + 2 * sl] = __floats2half2_rn(rx, ry);
    } else {
      *(float2*)&out[(size_t)mynode * D + 2 * sl] = make_float2(rx, ry);
    }
  }
}

// ---------------- Global mean pool (batch is sorted) ----------------

__global__ __launch_bounds__(256) void pool_k(const float* __restrict__ h,
                                              const int* __restrict__ batch,
                                              float* __restrict__ psum,
                                              float* __restrict__ pcnt, int n) {
  int lane  = threadIdx.x & 63;
  int wid   = __builtin_amdgcn_readfirstlane((blockIdx.x * blockDim.x + threadIdx.x) >> 6);
  int start = wid * 64;
  if (start >= n) return;
  int end = min(start + 64, n);
  int cur = batch[start];
  float sum = 0.f;
  int run = 0;
  for (int i = start; i < end; ++i) {
    int g = batch[i];
    if (g != cur) {
      atomicAdd(&psum[cur * D + lane], sum);
      if (lane == 0) atomicAdd(&pcnt[cur], (float)run);
      sum = 0.f; run = 0; cur = g;
    }
    sum += h[(size_t)i * D + lane];
    run += 1;
  }
  atomicAdd(&psum[cur * D + lane], sum);
  if (lane == 0) atomicAdd(&pcnt[cur], (float)run);
}

__global__ void pooldiv_k(const float* __restrict__ psum, const float* __restrict__ pcnt,
                          float* __restrict__ hg) {
  int t = blockIdx.x * blockDim.x + threadIdx.x;
  if (t < 64 * D) hg[t] = psum[t] / fmaxf(pcnt[t >> 6], 1.0f);
}

// ---------------- launcher ----------------

extern "C" void kernel_launch(void* const* d_in, const int* in_sizes, int n_in,
                              void* d_out, int out_size, void* d_ws, size_t ws_size,
                              hipStream_t stream) {
  const float* x   = (const float*)d_in[0];
  const int*   ei  = (const int*)d_in[1];
  const int*   bat = (const int*)d_in[2];
  const float* W1  = (const float*)d_in[3];
  const float* W2  = (const float*)d_in[4];
  const float* W3  = (const float*)d_in[5];
  const float* b1  = (const float*)d_in[6];
  const float* b2  = (const float*)d_in[7];
  const float* b3  = (const float*)d_in[8];
  const float* g1  = (const float*)d_in[9];
  const float* be1 = (const float*)d_in[10];
  const float* rm1 = (const float*)d_in[11];
  const float* rv1 = (const float*)d_in[12];
  const float* g2  = (const float*)d_in[13];
  const float* be2 = (const float*)d_in[14];
  const float* rm2 = (const float*)d_in[15];
  const float* rv2 = (const float*)d_in[16];

  const int n = in_sizes[0] / D;   // 100000
  const int e = in_sizes[1] / 2;   // 1200000
  const int* src = ei;
  const int* dst = ei + e;
  const int nbk = (n + BK_W - 1) >> BK_SHIFT;   // 196

  char* ws = (char*)d_ws;
  size_t off = 0;
  auto alloc = [&](size_t bytes) -> void* {
    void* p = ws + off;
    off = (off + bytes + 255) & ~(size_t)255;
    return p;
  };
  __half* buf16 = (__half*)alloc((size_t)n * D * 2);   // agg fp16 out (layers 1,2)
  int*    pairs = (int*)alloc((size_t)NBMAX * BK_CAP * 4);  // bucket slabs
  __half* hbuf  = (__half*)alloc((size_t)n * D * 2);   // gemm fp16 out (dis-scaled)
  int*    cnt   = (int*)alloc((size_t)n * 4);
  int*    rp    = (int*)alloc((size_t)(n + 1) * 4);
  float*  dis   = (float*)alloc((size_t)n * 4);
  int*    col   = (int*)alloc((size_t)e * 4);
  int*    bcnt  = (int*)alloc(NBMAX * 4);
  int*    bsum  = (int*)alloc(512 * 4);
  int*    boff  = (int*)alloc(512 * 4);
  float*  scsh  = (float*)alloc(6 * 64 * 4);
  float*  psum  = (float*)alloc(64 * D * 4);
  float*  pcnt  = (float*)alloc(64 * 4);

  float* hout = (float*)d_out;
  float* hg   = (float*)d_out + (size_t)n * D;

  hipMemsetAsync(bcnt, 0, NBMAX * 4, stream);
  hipMemsetAsync(psum, 0, 64 * D * 4, stream);
  hipMemsetAsync(pcnt, 0, 64 * 4, stream);

  const int nb = (n + 255) / 256;
  bucket_k<<<(e + CHUNK - 1) / CHUNK, 256, 0, stream>>>(src, dst, bcnt, pairs, e, nbk);
  bhist_k<<<nbk, 256, 0, stream>>>(bcnt, pairs, cnt, n);
  scan_a_k<<<nb, 256, 0, stream>>>(cnt, rp, bsum, n);
  scan_b_k<<<1, 512, 0, stream>>>(bsum, boff, nb);
  scan_c_k<<<nb, 256, 0, stream>>>(cnt, rp, boff, dis, n, e);
  place_k<<<nbk, 256, 0, stream>>>(bcnt, pairs, rp, col, n);
  bnprep_k<<<1, 192, 0, stream>>>(b1, b2, b3, g1, be1, rm1, rv1, g2, be2, rm2, rv2, scsh);

  const int gemm_blocks = (n + GT_R - 1) / GT_R;
  const int agg_waves   = (n + 1) / 2;
  const int agg_blocks  = (agg_waves * 64 + 255) / 256;

  // layer 1
  gemm_k<float><<<gemm_blocks, 256, 0, stream>>>(x, W1, dis, hbuf, n);
  agg_k<true, __half><<<agg_blocks, 256, 0, stream>>>(hbuf, rp, col, dis, scsh + 0 * 128, buf16, n);
  // layer 2
  gemm_k<__half><<<gemm_blocks, 256, 0, stream>>>(buf16, W2, dis, hbuf, n);
  agg_k<true, __half><<<agg_blocks, 256, 0, stream>>>(hbuf, rp, col, dis, scsh + 1 * 128, buf16, n);
  // layer 3
  gemm_k<__half><<<gemm_blocks, 256, 0, stream>>>(buf16, W3, dis, hbuf, n);
  agg_k<false, float><<<agg_blocks, 256, 0, stream>>>(hbuf, rp, col, dis, scsh + 2 * 128, hout, n);

  // pooling
  const int pool_waves = (n + 63) / 64;
  pool_k<<<(pool_waves * 64 + 255) / 256, 256, 0, stream>>>(hout, bat, psum, pcnt, n);
  pooldiv_k<<<(64 * D + 255) / 256, 256, 0, stream>>>(psum, pcnt, hg);
}

// Round 6
// 370.884 us; speedup vs baseline: 1.1398x; 1.1398x over previous
//
#include <hip/hip_runtime.h>
#include <hip/hip_fp16.h>

#define D 64
#define EPS 1e-5f

// CSR bucketing params: buckets of 512 consecutive dst nodes
#define BK_SHIFT 9
#define BK_W 512
#define NBMAX 256        // supports n up to 131072
#define BK_CAP 8192      // avg 6144 edges/bucket
#define CHUNK 4096       // edges per bucket_k block

// ---------------- Phase A: bucketize edges; pack (src<<9 | dst_local) ----------------

__global__ __launch_bounds__(256) void bucket_k(const int* __restrict__ src,
                                                const int* __restrict__ dst,
                                                int* __restrict__ bcnt,
                                                int* __restrict__ pairs,
                                                int e, int nbk) {
  __shared__ int hcnt[NBMAX];
  __shared__ int hbase[NBMAX];
  const int t = threadIdx.x;
  const int e0 = blockIdx.x * CHUNK;
  const int e1 = min(e0 + CHUNK, e);
  for (int i = t; i < nbk; i += 256) hcnt[i] = 0;
  __syncthreads();
  for (int i = e0 + t; i < e1; i += 256)
    atomicAdd(&hcnt[dst[i] >> BK_SHIFT], 1);
  __syncthreads();
  for (int i = t; i < nbk; i += 256) {
    int c = hcnt[i];
    hbase[i] = c ? atomicAdd(&bcnt[i], c) : 0;
    hcnt[i] = 0;   // reuse as cursor
  }
  __syncthreads();
  for (int i = e0 + t; i < e1; i += 256) {
    int s = src[i], d = dst[i];
    int b = d >> BK_SHIFT;
    int r = hbase[b] + atomicAdd(&hcnt[b], 1);
    if (r < BK_CAP) pairs[(size_t)b * BK_CAP + r] = (s << BK_SHIFT) | (d & (BK_W - 1));
  }
}

// ---------------- bucket-level exclusive scan (196 values, 1 block) ----------------

__global__ void bscan_k(const int* __restrict__ bcnt, int* __restrict__ bbase, int nbk) {
  __shared__ int sm[256];
  int t = threadIdx.x;
  int v = (t < nbk) ? bcnt[t] : 0;
  sm[t] = v; __syncthreads();
  for (int off = 1; off < 256; off <<= 1) {
    int x = (t >= off) ? sm[t - off] : 0; __syncthreads();
    sm[t] += x; __syncthreads();
  }
  if (t < nbk) bbase[t] = sm[t] - v;
}

// ---------------- Fused: per-bucket hist -> scan -> rp/dis -> place -> col -----------

__global__ __launch_bounds__(256) void bucket2csr_k(const int* __restrict__ bcnt,
                                                    const int* __restrict__ bbase,
                                                    const int* __restrict__ pairs,
                                                    int* __restrict__ rp,
                                                    float* __restrict__ dis,
                                                    int* __restrict__ col,
                                                    int n, int etot) {
  __shared__ int h[BK_W];        // per-node counts (kept for dis)
  __shared__ int cur[BK_W];      // exclusive scan -> cursors
  __shared__ int s1[256], s2[256];
  __shared__ int stage[BK_CAP];
  const int b = blockIdx.x, t = threadIdx.x;
  const int base = b << BK_SHIFT;
  const int e0 = bbase[b];
  const int m = min(bcnt[b], BK_CAP);

  h[t] = 0; h[t + 256] = 0;
  __syncthreads();
  const int* p = pairs + (size_t)b * BK_CAP;
  for (int i = t; i < m; i += 256) atomicAdd(&h[p[i] & (BK_W - 1)], 1);
  __syncthreads();

  // exclusive scan of h[0..511]: two 256-wide inclusive scans + offset
  s1[t] = h[t]; s2[t] = h[t + 256];
  __syncthreads();
  for (int off = 1; off < 256; off <<= 1) {
    int x1 = (t >= off) ? s1[t - off] : 0;
    int x2 = (t >= off) ? s2[t - off] : 0;
    __syncthreads();
    s1[t] += x1; s2[t] += x2;
    __syncthreads();
  }
  const int tot1 = s1[255];
  cur[t]       = s1[t] - h[t];
  cur[t + 256] = tot1 + s2[t] - h[t + 256];
  {
    int n1 = base + t, n2 = base + t + 256;
    if (n1 < n) { rp[n1] = e0 + cur[t];       dis[n1] = rsqrtf((float)h[t] + 1.0f); }
    if (n2 < n) { rp[n2] = e0 + cur[t + 256]; dis[n2] = rsqrtf((float)h[t + 256] + 1.0f); }
  }
  if (b == 0 && t == 0) rp[n] = etot;
  __syncthreads();

  for (int i = t; i < m; i += 256) {
    int pk = p[i];
    int r = atomicAdd(&cur[pk & (BK_W - 1)], 1);
    stage[r] = pk >> BK_SHIFT;
  }
  __syncthreads();
  for (int i = t; i < m; i += 256) col[e0 + i] = stage[i];
}

// ---------------- BN/bias folding ----------------

__global__ void bnprep_k(const float* __restrict__ b1, const float* __restrict__ b2,
                         const float* __restrict__ b3,
                         const float* __restrict__ g1, const float* __restrict__ be1,
                         const float* __restrict__ rm1, const float* __restrict__ rv1,
                         const float* __restrict__ g2, const float* __restrict__ be2,
                         const float* __restrict__ rm2, const float* __restrict__ rv2,
                         float* __restrict__ scsh) {
  int t = threadIdx.x;
  int j = t & 63, l = t >> 6;
  float sc, sh;
  if (l == 0)      { sc = g1[j] * rsqrtf(rv1[j] + EPS); sh = (b1[j] - rm1[j]) * sc + be1[j]; }
  else if (l == 1) { sc = g2[j] * rsqrtf(rv2[j] + EPS); sh = (b2[j] - rm2[j]) * sc + be2[j]; }
  else             { sc = 1.0f;                          sh = b3[j]; }
  scsh[l * 128 + j] = sc;
  scsh[l * 128 + 64 + j] = sh;
}

// ---------------- GEMM: out[r] = dis[r] * (in[r] @ W), fp16 out, fp32/fp16 in --------

#define GT_R 128
#define XT_LD 132

__device__ inline float ld1(const float* p)  { return *p; }
__device__ inline float ld1(const __half* p) { return __half2float(*p); }

template <typename InT>
__global__ __launch_bounds__(256) void gemm_k(const InT* __restrict__ in,
                                              const float* __restrict__ W,
                                              const float* __restrict__ dis,
                                              __half* __restrict__ out, int nrows) {
  __shared__ float ws[64 * 64];
  __shared__ float xt[64 * XT_LD];
  __shared__ float dtile[GT_R];

  const int t    = threadIdx.x;
  const int lane = t & 63;
  const int w    = t >> 6;
  const int row0 = blockIdx.x * GT_R;

  for (int i = t; i < 1024; i += 256)
    ((float4*)ws)[i] = ((const float4*)W)[i];

  if (t < GT_R) {
    int r = row0 + t;
    dtile[t] = (r < nrows) ? dis[r] : 0.f;
  }

#pragma unroll
  for (int j = 0; j < 8; ++j) {
    int Q = w + 4 * j;
    int r = row0 + 4 * Q;
    float4 v;
    v.x = (r + 0 < nrows) ? ld1(&in[(size_t)(r + 0) * D + lane]) : 0.f;
    v.y = (r + 1 < nrows) ? ld1(&in[(size_t)(r + 1) * D + lane]) : 0.f;
    v.z = (r + 2 < nrows) ? ld1(&in[(size_t)(r + 2) * D + lane]) : 0.f;
    v.w = (r + 3 < nrows) ? ld1(&in[(size_t)(r + 3) * D + lane]) : 0.f;
    *(float4*)&xt[lane * XT_LD + 4 * Q] = v;
  }
  __syncthreads();

  const int cq = (t & 15) * 4;
  const int rg = (t >> 4) * 8;
  float acc[8][4] = {};

#pragma unroll 4
  for (int k = 0; k < 64; ++k) {
    float4 b   = *(const float4*)&ws[k * 64 + cq];
    float4 alo = *(const float4*)&xt[k * XT_LD + rg];
    float4 ahi = *(const float4*)&xt[k * XT_LD + rg + 4];
    const float ar[8] = {alo.x, alo.y, alo.z, alo.w, ahi.x, ahi.y, ahi.z, ahi.w};
#pragma unroll
    for (int i = 0; i < 8; ++i) {
      acc[i][0] = fmaf(ar[i], b.x, acc[i][0]);
      acc[i][1] = fmaf(ar[i], b.y, acc[i][1]);
      acc[i][2] = fmaf(ar[i], b.z, acc[i][2]);
      acc[i][3] = fmaf(ar[i], b.w, acc[i][3]);
    }
  }

#pragma unroll
  for (int i = 0; i < 8; ++i) {
    int r = row0 + rg + i;
    if (r < nrows) {
      float dsc = dtile[rg + i];
      union { __half2 h[2]; float2 f; } u;
      u.h[0] = __floats2half2_rn(dsc * acc[i][0], dsc * acc[i][1]);
      u.h[1] = __floats2half2_rn(dsc * acc[i][2], dsc * acc[i][3]);
      *(float2*)&out[(size_t)r * D + cq] = u.f;
    }
  }
}

// ---------------- Aggregation: 1 node/wave, readlane broadcast, unroll 8 ------------
// h2s pre-scaled by dis[src]. All 8 loads of a batch issue unconditionally
// (clamped lane -> valid node), adds predicated -> no serial-latency tail.

template <bool RELU, typename OutT>
__global__ __launch_bounds__(256) void agg_k(const __half* __restrict__ h2s,
                                             const int* __restrict__ rp,
                                             const int* __restrict__ col,
                                             const float* __restrict__ dis,
                                             const float* __restrict__ scsh,
                                             OutT* __restrict__ out, int n) {
  const int lane = threadIdx.x & 63;
  const int node = __builtin_amdgcn_readfirstlane((blockIdx.x * blockDim.x + threadIdx.x) >> 6);
  if (node >= n) return;

  float a0 = __half2float(h2s[(size_t)node * D + lane]);   // self-loop term
  float a1 = 0.f, a2 = 0.f, a3 = 0.f, a4 = 0.f, a5 = 0.f, a6 = 0.f, a7 = 0.f;

  int p  = rp[node];
  int p1 = rp[node + 1];
  while (p < p1) {
    const int m = min(p1 - p, 64);      // wave-uniform
    int idxv = 0;
    if (lane < m) idxv = col[p + lane]; // one vector load = up to 64 indices
    for (int e = 0; e < m; e += 8) {
      int s0 = __builtin_amdgcn_readlane(idxv, (e + 0) & 63);
      int s1 = __builtin_amdgcn_readlane(idxv, (e + 1) & 63);
      int s2 = __builtin_amdgcn_readlane(idxv, (e + 2) & 63);
      int s3 = __builtin_amdgcn_readlane(idxv, (e + 3) & 63);
      int s4 = __builtin_amdgcn_readlane(idxv, (e + 4) & 63);
      int s5 = __builtin_amdgcn_readlane(idxv, (e + 5) & 63);
      int s6 = __builtin_amdgcn_readlane(idxv, (e + 6) & 63);
      int s7 = __builtin_amdgcn_readlane(idxv, (e + 7) & 63);
      float v0 = __half2float(h2s[(size_t)s0 * D + lane]);
      float v1 = __half2float(h2s[(size_t)s1 * D + lane]);
      float v2 = __half2float(h2s[(size_t)s2 * D + lane]);
      float v3 = __half2float(h2s[(size_t)s3 * D + lane]);
      float v4 = __half2float(h2s[(size_t)s4 * D + lane]);
      float v5 = __half2float(h2s[(size_t)s5 * D + lane]);
      float v6 = __half2float(h2s[(size_t)s6 * D + lane]);
      float v7 = __half2float(h2s[(size_t)s7 * D + lane]);
      a0 += v0;                               // e+0 < m always
      a1 += (e + 1 < m) ? v1 : 0.f;
      a2 += (e + 2 < m) ? v2 : 0.f;
      a3 += (e + 3 < m) ? v3 : 0.f;
      a4 += (e + 4 < m) ? v4 : 0.f;
      a5 += (e + 5 < m) ? v5 : 0.f;
      a6 += (e + 6 < m) ? v6 : 0.f;
      a7 += (e + 7 < m) ? v7 : 0.f;
    }
    p += m;
  }

  float tot = ((a0 + a1) + (a2 + a3)) + ((a4 + a5) + (a6 + a7));
  const float di = dis[node];
  float r = fmaf(di * tot, scsh[lane], scsh[64 + lane]);
  if (RELU) r = fmaxf(r, 0.0f);
  if constexpr (sizeof(OutT) == 2) {
    out[(size_t)node * D + lane] = __float2half_rn(r);
  } else {
    out[(size_t)node * D + lane] = r;
  }
}

// ---------------- Global mean pool (batch is sorted) ----------------

__global__ __launch_bounds__(256) void pool_k(const float* __restrict__ h,
                                              const int* __restrict__ batch,
                                              float* __restrict__ psum,
                                              float* __restrict__ pcnt, int n) {
  int lane  = threadIdx.x & 63;
  int wid   = __builtin_amdgcn_readfirstlane((blockIdx.x * blockDim.x + threadIdx.x) >> 6);
  int start = wid * 64;
  if (start >= n) return;
  int end = min(start + 64, n);
  int cur = batch[start];
  float sum = 0.f;
  int run = 0;
  for (int i = start; i < end; ++i) {
    int g = batch[i];
    if (g != cur) {
      atomicAdd(&psum[cur * D + lane], sum);
      if (lane == 0) atomicAdd(&pcnt[cur], (float)run);
      sum = 0.f; run = 0; cur = g;
    }
    sum += h[(size_t)i * D + lane];
    run += 1;
  }
  atomicAdd(&psum[cur * D + lane], sum);
  if (lane == 0) atomicAdd(&pcnt[cur], (float)run);
}

__global__ void pooldiv_k(const float* __restrict__ psum, const float* __restrict__ pcnt,
                          float* __restrict__ hg) {
  int t = blockIdx.x * blockDim.x + threadIdx.x;
  if (t < 64 * D) hg[t] = psum[t] / fmaxf(pcnt[t >> 6], 1.0f);
}

// ---------------- launcher ----------------

extern "C" void kernel_launch(void* const* d_in, const int* in_sizes, int n_in,
                              void* d_out, int out_size, void* d_ws, size_t ws_size,
                              hipStream_t stream) {
  const float* x   = (const float*)d_in[0];
  const int*   ei  = (const int*)d_in[1];
  const int*   bat = (const int*)d_in[2];
  const float* W1  = (const float*)d_in[3];
  const float* W2  = (const float*)d_in[4];
  const float* W3  = (const float*)d_in[5];
  const float* b1  = (const float*)d_in[6];
  const float* b2  = (const float*)d_in[7];
  const float* b3  = (const float*)d_in[8];
  const float* g1  = (const float*)d_in[9];
  const float* be1 = (const float*)d_in[10];
  const float* rm1 = (const float*)d_in[11];
  const float* rv1 = (const float*)d_in[12];
  const float* g2  = (const float*)d_in[13];
  const float* be2 = (const float*)d_in[14];
  const float* rm2 = (const float*)d_in[15];
  const float* rv2 = (const float*)d_in[16];

  const int n = in_sizes[0] / D;   // 100000
  const int e = in_sizes[1] / 2;   // 1200000
  const int* src = ei;
  const int* dst = ei + e;
  const int nbk = (n + BK_W - 1) >> BK_SHIFT;   // 196

  char* ws = (char*)d_ws;
  size_t off = 0;
  auto alloc = [&](size_t bytes) -> void* {
    void* p = ws + off;
    off = (off + bytes + 255) & ~(size_t)255;
    return p;
  };
  __half* buf16 = (__half*)alloc((size_t)n * D * 2);        // agg fp16 out (layers 1,2)
  int*    pairs = (int*)alloc((size_t)NBMAX * BK_CAP * 4);  // bucket slabs
  __half* hbuf  = (__half*)alloc((size_t)n * D * 2);        // gemm fp16 out (dis-scaled)
  int*    rp    = (int*)alloc((size_t)(n + 1) * 4);
  float*  dis   = (float*)alloc((size_t)n * 4);
  int*    col   = (int*)alloc((size_t)e * 4);
  int*    bcnt  = (int*)alloc(NBMAX * 4);
  int*    bbase = (int*)alloc(NBMAX * 4);
  float*  scsh  = (float*)alloc(6 * 64 * 4);
  float*  psum  = (float*)alloc(64 * D * 4);
  float*  pcnt  = (float*)alloc(64 * 4);

  float* hout = (float*)d_out;
  float* hg   = (float*)d_out + (size_t)n * D;

  hipMemsetAsync(bcnt, 0, NBMAX * 4, stream);
  hipMemsetAsync(psum, 0, 64 * D * 4, stream);
  hipMemsetAsync(pcnt, 0, 64 * 4, stream);

  bucket_k<<<(e + CHUNK - 1) / CHUNK, 256, 0, stream>>>(src, dst, bcnt, pairs, e, nbk);
  bscan_k<<<1, 256, 0, stream>>>(bcnt, bbase, nbk);
  bucket2csr_k<<<nbk, 256, 0, stream>>>(bcnt, bbase, pairs, rp, dis, col, n, e);
  bnprep_k<<<1, 192, 0, stream>>>(b1, b2, b3, g1, be1, rm1, rv1, g2, be2, rm2, rv2, scsh);

  const int gemm_blocks = (n + GT_R - 1) / GT_R;
  const int agg_blocks  = (n * 64 + 255) / 256;

  // layer 1
  gemm_k<float><<<gemm_blocks, 256, 0, stream>>>(x, W1, dis, hbuf, n);
  agg_k<true, __half><<<agg_blocks, 256, 0, stream>>>(hbuf, rp, col, dis, scsh + 0 * 128, buf16, n);
  // layer 2
  gemm_k<__half><<<gemm_blocks, 256, 0, stream>>>(buf16, W2, dis, hbuf, n);
  agg_k<true, __half><<<agg_blocks, 256, 0, stream>>>(hbuf, rp, col, dis, scsh + 1 * 128, buf16, n);
  // layer 3
  gemm_k<__half><<<gemm_blocks, 256, 0, stream>>>(buf16, W3, dis, hbuf, n);
  agg_k<false, float><<<agg_blocks, 256, 0, stream>>>(hbuf, rp, col, dis, scsh + 2 * 128, hout, n);

  // pooling
  const int pool_waves = (n + 63) / 64;
  pool_k<<<(pool_waves * 64 + 255) / 256, 256, 0, stream>>>(hout, bat, psum, pcnt, n);
  pooldiv_k<<<(64 * D + 255) / 256, 256, 0, stream>>>(psum, pcnt, hg);
}